// Round 3
// baseline (497.751 us; speedup 1.0000x reference)
//
#include <hip/hip_runtime.h>
#include <stdint.h>

#define B 16
#define N 20000
#define D 256
#define K 300

// ---------------------------------------------------------------------------
// Kernel 1: per-token score = dot(token, W) + b -> monotone uint32 key.
// One wave handles 8 tokens. Per-lane partial dots are combined with a
// transposed butterfly (10 shuffles total): after 3 merge levels (xor 1,2,4)
// lane l holds the partial for token (l&7); 3 more xor-adds (8,16,32) finish
// the reduction. Lanes 0..7 store 8 contiguous keys.
// ---------------------------------------------------------------------------
__global__ __launch_bounds__(256) void score_kernel(
    const float* __restrict__ tokens, const float* __restrict__ W,
    const float* __restrict__ bias, uint32_t* __restrict__ keys) {
  int wid = (blockIdx.x * blockDim.x + threadIdx.x) >> 6;  // wave id
  int lane = threadIdx.x & 63;
  int tb = wid * 8;  // first of 8 tokens
  if (tb >= B * N) return;
  const float4 w4 = ((const float4*)W)[lane];
  const float4* tp = (const float4*)(tokens + (size_t)tb * D);
  float d[8];
#pragma unroll
  for (int j = 0; j < 8; ++j) {
    float4 a = tp[j * 64 + lane];
    d[j] = a.x * w4.x + a.y * w4.y + a.z * w4.z + a.w * w4.w;
  }
  // Merge level xor=1: token bit0 <- lane bit0.
  float m0, m1, m2, m3, s, r;
  s = (lane & 1) ? d[0] : d[1];
  r = __shfl_xor(s, 1, 64);
  m0 = ((lane & 1) ? d[1] : d[0]) + r;
  s = (lane & 1) ? d[2] : d[3];
  r = __shfl_xor(s, 1, 64);
  m1 = ((lane & 1) ? d[3] : d[2]) + r;
  s = (lane & 1) ? d[4] : d[5];
  r = __shfl_xor(s, 1, 64);
  m2 = ((lane & 1) ? d[5] : d[4]) + r;
  s = (lane & 1) ? d[6] : d[7];
  r = __shfl_xor(s, 1, 64);
  m3 = ((lane & 1) ? d[7] : d[6]) + r;
  // Merge level xor=2: token bit1 <- lane bit1.
  float e0, e1;
  s = (lane & 2) ? m0 : m1;
  r = __shfl_xor(s, 2, 64);
  e0 = ((lane & 2) ? m1 : m0) + r;
  s = (lane & 2) ? m2 : m3;
  r = __shfl_xor(s, 2, 64);
  e1 = ((lane & 2) ? m3 : m2) + r;
  // Merge level xor=4: token bit2 <- lane bit2.
  s = (lane & 4) ? e0 : e1;
  r = __shfl_xor(s, 4, 64);
  float f = ((lane & 4) ? e1 : e0) + r;
  // Finish reduction across lane bits 3..5 (same token).
  f += __shfl_xor(f, 8, 64);
  f += __shfl_xor(f, 16, 64);
  f += __shfl_xor(f, 32, 64);
  if (lane < 8) {
    uint32_t u = __float_as_uint(f + bias[0]);
    keys[tb + lane] = (u & 0x80000000u) ? ~u : (u | 0x80000000u);
  }
}

// ---------------------------------------------------------------------------
// Kernel 2: per-batch top-K. MSB-first 4x8-bit radix select; wave-aggregated
// histogram atomics (ballot leader loop); wave-parallel suffix scan; collect
// >= threshold; rank-selection write (no bitonic sort). One 512-thread block
// per batch.
// ---------------------------------------------------------------------------
__global__ __launch_bounds__(512) void topk_kernel(
    const uint32_t* __restrict__ keys_g, int* __restrict__ idx_out,
    float* __restrict__ out_idx_f) {
  __shared__ __align__(16) uint32_t hist[256];
  __shared__ uint64_t cand[512];
  __shared__ uint32_t s_prefix, s_remaining, s_prefix_next, s_rem_next,
      cand_cnt;

  const int b = blockIdx.x;
  const int t = threadIdx.x;
  const int lane = t & 63;
  const uint4* keys4 = (const uint4*)(keys_g + (size_t)b * N);
  const int N4 = N / 4;  // 5000; padded loop bound 5120 = 10 trips for all t

  if (t == 0) {
    s_prefix = 0;
    s_remaining = K;
    cand_cnt = 0;
  }
  if (t < 256) hist[t] = 0;
  __syncthreads();

  for (int pass = 0; pass < 4; ++pass) {
    const int shift = 24 - pass * 8;
    const uint32_t prefix = s_prefix;
    const uint32_t pmask = (pass == 0) ? 0u : (0xFFFFFFFFu << (shift + 8));
    for (int i = t; i < 5120; i += 512) {  // uniform trip count (wave collectives)
      const bool in = i < N4;
      uint4 kv;
      if (in) kv = keys4[i];
      uint32_t ka[4] = {kv.x, kv.y, kv.z, kv.w};
#pragma unroll
      for (int j = 0; j < 4; ++j) {
        const bool p = in && ((ka[j] & pmask) == prefix);
        const uint32_t bin = (ka[j] >> shift) & 255u;
        unsigned long long todo = __ballot(p);
        while (todo) {
          const int leader = __ffsll(todo) - 1;
          const uint32_t lbin = __shfl(bin, leader, 64);
          const unsigned long long same = __ballot(p && (bin == lbin));
          if (lane == leader) atomicAdd(&hist[lbin], (uint32_t)__popcll(same));
          todo &= ~same;
        }
      }
    }
    __syncthreads();
    // Wave 0: parallel suffix-scan over 256 bins (4 bins per lane).
    if (t < 64) {
      uint4 h = ((const uint4*)hist)[t];
      uint32_t hv0 = h.x, hv1 = h.y, hv2 = h.z, hv3 = h.w;
      uint32_t sum4 = hv0 + hv1 + hv2 + hv3;
      uint32_t s = sum4;
#pragma unroll
      for (int off = 1; off < 64; off <<= 1) {
        uint32_t v = __shfl_down(s, off, 64);
        if (t + off < 64) s += v;
      }
      uint32_t rem = s_remaining;
      uint32_t acc = s - sum4;  // count in bins >= 4(t+1)
      uint32_t hv[4] = {hv0, hv1, hv2, hv3};
#pragma unroll
      for (int j = 3; j >= 0; --j) {
        uint32_t ge = acc + hv[j];
        if (acc < rem && rem <= ge) {
          s_prefix_next = prefix | ((uint32_t)(4 * t + j) << shift);
          s_rem_next = rem - acc;
        }
        acc = ge;
      }
    }
    __syncthreads();
    if (t == 0) {
      s_prefix = s_prefix_next;
      s_remaining = s_rem_next;
    }
    if (t < 256) hist[t] = 0;  // ready for next pass
    __syncthreads();
  }
  const uint32_t T = s_prefix;  // exact K-th largest key

  // Collect all keys >= T (count >= K; between K and K+ties).
  for (int i = t; i < 5120; i += 512) {
    if (i < N4) {
      uint4 kv = keys4[i];
      uint32_t ka[4] = {kv.x, kv.y, kv.z, kv.w};
#pragma unroll
      for (int j = 0; j < 4; ++j)
        if (ka[j] >= T) {
          uint32_t pos = atomicAdd(&cand_cnt, 1u);
          if (pos < 512)
            cand[pos] = ((uint64_t)ka[j] << 32) |
                        (uint64_t)(0xFFFFFFFFu - (uint32_t)(4 * i + j));
        }
    }
  }
  __syncthreads();

  // Rank selection: rank = #items better than mine (key desc, idx asc).
  // Items are distinct (distinct idx) -> ranks unique -> direct scatter.
  int cnt = (int)cand_cnt;
  if (cnt > 512) cnt = 512;
  if (t < cnt) {
    const uint64_t mine = cand[t];
    int rank = 0;
    for (int i = 0; i < cnt; ++i) rank += (cand[i] > mine) ? 1 : 0;
    if (rank < K) {
      int idx = (int)(0xFFFFFFFFu - (uint32_t)(mine & 0xFFFFFFFFu));
      idx_out[b * K + rank] = idx;
      out_idx_f[b * K + rank] = (float)idx;
    }
  }
}

// ---------------------------------------------------------------------------
// Kernel 3: gather selected token vectors. One wave per (b, r).
// ---------------------------------------------------------------------------
__global__ __launch_bounds__(256) void gather_kernel(
    const float* __restrict__ tokens, const int* __restrict__ idx,
    float* __restrict__ out0) {
  int gwave = (blockIdx.x * blockDim.x + threadIdx.x) >> 6;  // 0..B*K-1
  int lane = threadIdx.x & 63;
  if (gwave >= B * K) return;
  int b = gwave / K;
  int id = idx[gwave];
  float4 v = ((const float4*)(tokens + ((size_t)b * N + id) * D))[lane];
  ((float4*)(out0 + (size_t)gwave * D))[lane] = v;
}

extern "C" void kernel_launch(void* const* d_in, const int* in_sizes, int n_in,
                              void* d_out, int out_size, void* d_ws,
                              size_t ws_size, hipStream_t stream) {
  const float* tokens = (const float*)d_in[0];
  const float* W = (const float*)d_in[1];
  const float* bias = (const float*)d_in[2];

  float* out_sel = (float*)d_out;                  // [B, K, D] float32
  float* out_idx_f = out_sel + (size_t)B * K * D;  // [B, K] indices as float

  uint32_t* keys = (uint32_t*)d_ws;  // B*N*4 = 1.28 MB
  int* idx = (int*)((char*)d_ws + (size_t)B * N * sizeof(uint32_t));

  // 8 tokens/wave, 4 waves/block -> 32 tokens/block; B*N = 320000 exact.
  score_kernel<<<(B * N) / 32, 256, 0, stream>>>(tokens, W, bias, keys);
  topk_kernel<<<B, 512, 0, stream>>>(keys, idx, out_idx_f);
  gather_kernel<<<(B * K + 3) / 4, 256, 0, stream>>>(tokens, idx, out_sel);
}

// Round 4
// 447.546 us; speedup vs baseline: 1.1122x; 1.1122x over previous
//
#include <hip/hip_runtime.h>
#include <stdint.h>

#define B 16
#define N 20000
#define D 256
#define K 300

// ---------------------------------------------------------------------------
// Kernel 1: per-token score = dot(token, W) + b -> monotone uint32 key.
// One wave handles 4 tokens (4 independent float4 loads in flight per lane).
// Lane 0 stores 4 keys as one uint4. (R2 version — best measured.)
// ---------------------------------------------------------------------------
__global__ __launch_bounds__(256) void score_kernel(
    const float* __restrict__ tokens, const float* __restrict__ W,
    const float* __restrict__ bias, uint32_t* __restrict__ keys) {
  int wid = (blockIdx.x * blockDim.x + threadIdx.x) >> 6;  // wave id
  int lane = threadIdx.x & 63;
  int tb = wid * 4;  // first of 4 tokens
  if (tb >= B * N) return;
  const float4 w4 = ((const float4*)W)[lane];
  const float4* tp = (const float4*)(tokens + (size_t)tb * D);
  float4 a0 = tp[lane];
  float4 a1 = tp[64 + lane];
  float4 a2 = tp[128 + lane];
  float4 a3 = tp[192 + lane];
  float d0 = a0.x * w4.x + a0.y * w4.y + a0.z * w4.z + a0.w * w4.w;
  float d1 = a1.x * w4.x + a1.y * w4.y + a1.z * w4.z + a1.w * w4.w;
  float d2 = a2.x * w4.x + a2.y * w4.y + a2.z * w4.z + a2.w * w4.w;
  float d3 = a3.x * w4.x + a3.y * w4.y + a3.z * w4.z + a3.w * w4.w;
#pragma unroll
  for (int off = 32; off >= 1; off >>= 1) {
    d0 += __shfl_xor(d0, off, 64);
    d1 += __shfl_xor(d1, off, 64);
    d2 += __shfl_xor(d2, off, 64);
    d3 += __shfl_xor(d3, off, 64);
  }
  if (lane == 0) {
    float bb = bias[0];
    uint32_t u0 = __float_as_uint(d0 + bb), u1 = __float_as_uint(d1 + bb);
    uint32_t u2 = __float_as_uint(d2 + bb), u3 = __float_as_uint(d3 + bb);
    uint4 kv;
    kv.x = (u0 & 0x80000000u) ? ~u0 : (u0 | 0x80000000u);
    kv.y = (u1 & 0x80000000u) ? ~u1 : (u1 | 0x80000000u);
    kv.z = (u2 & 0x80000000u) ? ~u2 : (u2 | 0x80000000u);
    kv.w = (u3 & 0x80000000u) ? ~u3 : (u3 | 0x80000000u);
    ((uint4*)keys)[wid] = kv;
  }
}

// ---------------------------------------------------------------------------
// Kernel 2: per-batch top-K. MSB-first 4x8-bit radix select; plain LDS-atomic
// histogram (different bins -> different banks -> parallel); wave-parallel
// suffix scan; collect >= threshold; rank-selection scatter (2 barriers, no
// bitonic). One 1024-thread block per batch (sweeps latency-bound; 5 trips).
// ---------------------------------------------------------------------------
__global__ __launch_bounds__(1024) void topk_kernel(
    const uint32_t* __restrict__ keys_g, int* __restrict__ idx_out,
    float* __restrict__ out_idx_f) {
  __shared__ __align__(16) uint32_t hist[256];
  __shared__ uint64_t cand[512];
  __shared__ uint32_t s_prefix, s_remaining, s_prefix_next, s_rem_next,
      cand_cnt;

  const int b = blockIdx.x;
  const int t = threadIdx.x;
  const uint4* keys4 = (const uint4*)(keys_g + (size_t)b * N);
  const int N4 = N / 4;  // 5000

  if (t == 0) {
    s_prefix = 0;
    s_remaining = K;
    cand_cnt = 0;
  }
  if (t < 256) hist[t] = 0;
  __syncthreads();

  for (int pass = 0; pass < 4; ++pass) {
    const int shift = 24 - pass * 8;
    const uint32_t prefix = s_prefix;
    const uint32_t pmask = (pass == 0) ? 0u : (0xFFFFFFFFu << (shift + 8));
    for (int i = t; i < N4; i += 1024) {
      uint4 kv = keys4[i];
      uint32_t ka[4] = {kv.x, kv.y, kv.z, kv.w};
#pragma unroll
      for (int j = 0; j < 4; ++j)
        if ((ka[j] & pmask) == prefix)
          atomicAdd(&hist[(ka[j] >> shift) & 255u], 1u);
    }
    __syncthreads();
    // Wave 0: parallel suffix-scan over 256 bins (4 bins per lane).
    if (t < 64) {
      uint4 h = ((const uint4*)hist)[t];
      uint32_t hv0 = h.x, hv1 = h.y, hv2 = h.z, hv3 = h.w;
      uint32_t sum4 = hv0 + hv1 + hv2 + hv3;
      uint32_t s = sum4;
#pragma unroll
      for (int off = 1; off < 64; off <<= 1) {
        uint32_t v = __shfl_down(s, off, 64);
        if (t + off < 64) s += v;
      }
      // s = count of keys in bins >= 4t (within current prefix)
      uint32_t rem = s_remaining;
      uint32_t acc = s - sum4;  // count in bins >= 4(t+1)
      uint32_t hv[4] = {hv0, hv1, hv2, hv3};
#pragma unroll
      for (int j = 3; j >= 0; --j) {
        uint32_t ge = acc + hv[j];
        if (acc < rem && rem <= ge) {
          s_prefix_next = prefix | ((uint32_t)(4 * t + j) << shift);
          s_rem_next = rem - acc;
        }
        acc = ge;
      }
    }
    __syncthreads();
    if (t == 0) {
      s_prefix = s_prefix_next;
      s_remaining = s_rem_next;
    }
    if (t < 256) hist[t] = 0;  // ready for next pass
    __syncthreads();
  }
  const uint32_t T = s_prefix;  // exact K-th largest key

  // Collect all keys >= T (count in [K, K+ties)).
  for (int i = t; i < N4; i += 1024) {
    uint4 kv = keys4[i];
    uint32_t ka[4] = {kv.x, kv.y, kv.z, kv.w};
#pragma unroll
    for (int j = 0; j < 4; ++j)
      if (ka[j] >= T) {
        uint32_t pos = atomicAdd(&cand_cnt, 1u);
        if (pos < 512)
          cand[pos] = ((uint64_t)ka[j] << 32) |
                      (uint64_t)(0xFFFFFFFFu - (uint32_t)(4 * i + j));
      }
  }
  __syncthreads();

  // Rank selection: rank = #items better than mine (key desc, idx asc).
  // Items are distinct (distinct idx) -> ranks unique -> direct scatter.
  // All threads read the same cand[i] each iter -> LDS broadcast, no conflict.
  int cnt = (int)cand_cnt;
  if (cnt > 512) cnt = 512;
  if (t < cnt) {
    const uint64_t mine = cand[t];
    int rank = 0;
    for (int i = 0; i < cnt; ++i) rank += (cand[i] > mine) ? 1 : 0;
    if (rank < K) {
      int idx = (int)(0xFFFFFFFFu - (uint32_t)(mine & 0xFFFFFFFFu));
      idx_out[b * K + rank] = idx;
      out_idx_f[b * K + rank] = (float)idx;
    }
  }
}

// ---------------------------------------------------------------------------
// Kernel 3: gather selected token vectors. One wave per (b, r).
// ---------------------------------------------------------------------------
__global__ __launch_bounds__(256) void gather_kernel(
    const float* __restrict__ tokens, const int* __restrict__ idx,
    float* __restrict__ out0) {
  int gwave = (blockIdx.x * blockDim.x + threadIdx.x) >> 6;  // 0..B*K-1
  int lane = threadIdx.x & 63;
  if (gwave >= B * K) return;
  int b = gwave / K;
  int id = idx[gwave];
  float4 v = ((const float4*)(tokens + ((size_t)b * N + id) * D))[lane];
  ((float4*)(out0 + (size_t)gwave * D))[lane] = v;
}

extern "C" void kernel_launch(void* const* d_in, const int* in_sizes, int n_in,
                              void* d_out, int out_size, void* d_ws,
                              size_t ws_size, hipStream_t stream) {
  const float* tokens = (const float*)d_in[0];
  const float* W = (const float*)d_in[1];
  const float* bias = (const float*)d_in[2];

  float* out_sel = (float*)d_out;                  // [B, K, D] float32
  float* out_idx_f = out_sel + (size_t)B * K * D;  // [B, K] indices as float

  uint32_t* keys = (uint32_t*)d_ws;  // B*N*4 = 1.28 MB
  int* idx = (int*)((char*)d_ws + (size_t)B * N * sizeof(uint32_t));

  // 4 tokens per wave, 4 waves per block -> 16 tokens/block.
  score_kernel<<<(B * N) / 16, 256, 0, stream>>>(tokens, W, bias, keys);
  topk_kernel<<<B, 1024, 0, stream>>>(keys, idx, out_idx_f);
  gather_kernel<<<(B * K + 3) / 4, 256, 0, stream>>>(tokens, idx, out_sel);
}